// Round 2
// baseline (93.715 us; speedup 1.0000x reference)
//
#include <hip/hip_runtime.h>

// out[s,d,b,j] = log( sum_i exp(x[s,d,b,i]) * acc[s,d,i,j] ) - log( sum_i acc[s,d,i,j] )
// 256 batched 256x256x256 GEMMs in linear space, bf16 MFMA, fp32 accumulate.
// Grid 512: block = (sd = bid&255, jhalf = bid>>8). Same-XCD pairing for L2 reuse of x.

#define NSC 32
#define NDC 8
#define NB  256
#define NI  256
#define NJ  256
#define JH  128   // j columns per block

typedef __attribute__((ext_vector_type(8))) short bf16x8;
typedef __attribute__((ext_vector_type(4))) float f32x4;

__device__ __forceinline__ unsigned short f2bf(float f) {
  unsigned int u = __float_as_uint(f);
  u += 0x7FFFu + ((u >> 16) & 1u);
  return (unsigned short)(u >> 16);
}

__global__ __launch_bounds__(512, 4)
void densesum_kernel(const float* __restrict__ x,
                     const float* __restrict__ acc,
                     float* __restrict__ out) {
  const int bid = blockIdx.x;
  const int sd  = bid & 255;                 // same sd on same XCD for both halves
  const int j0  = (bid >> 8) * JH;
  const float* xb = x   + (size_t)sd * NB * NI;
  const float* ab = acc + (size_t)sd * NI * NJ;
  float*       ob = out + (size_t)sd * NB * NJ;

  // A = exp(x) [256 b][64 k] bf16 ; B^T = acc^T [128 j][64 k] bf16.
  // 128B rows, XOR swizzle byte ^= ((row&7)<<4) -> conflict-free ds_read_b128.
  __shared__ unsigned short As[NB * 64];
  __shared__ unsigned short Bs[JH * 64];
  __shared__ float colpart[16 * JH];
  __shared__ float logS[JH];

  const int tid  = threadIdx.x;
  const int lane = tid & 63;
  const int wid  = tid >> 6;      // 8 waves
  const int wr   = wid >> 2;      // 0..1  (128-row strip of b)
  const int wc   = wid & 3;       // 0..3  (32-col strip of j)
  const int l15  = lane & 15;
  const int lk   = lane >> 4;     // 0..3

  f32x4 C[8][2];
  #pragma unroll
  for (int m = 0; m < 8; ++m)
    #pragma unroll
    for (int n = 0; n < 2; ++n)
      C[m][n] = (f32x4){0.f, 0.f, 0.f, 0.f};

  // per-thread j-column partial sums; thread's j set: jb + ((cc + r)&3)
  const int r = (lane >> 1) & 3;
  float bsum0 = 0.f, bsum1 = 0.f, bsum2 = 0.f, bsum3 = 0.f;

  for (int kc = 0; kc < 4; ++kc) {
    const int i0 = kc * 64;

    // ---- stage A: exp(x) -> bf16, [b][k] swizzled
    #pragma unroll
    for (int it = 0; it < 8; ++it) {
      int q  = tid + it * 512;              // 0..4095 quads
      int b  = q >> 4;                      // 0..255
      int c0 = (q & 15) * 4;                // 0..60
      const float4 xv = *reinterpret_cast<const float4*>(xb + (size_t)b * NI + i0 + c0);
      ushort4 h;
      h.x = f2bf(__expf(xv.x));
      h.y = f2bf(__expf(xv.y));
      h.z = f2bf(__expf(xv.z));
      h.w = f2bf(__expf(xv.w));
      *reinterpret_cast<ushort4*>(&As[b * 64 + (c0 ^ ((b & 7) << 3))]) = h;
    }

    // ---- stage B^T: acc -> bf16 transposed [j][k]; fused column sums.
    // Write order rotated by r so j&7 spans all 8 values per instruction
    // (unrotated: k is wave-constant and j&7 takes 2 values -> 32-way conflict).
    #pragma unroll
    for (int it = 0; it < 4; ++it) {
      int q  = tid + it * 512;              // 0..2047 quads
      int k  = q >> 5;                      // 0..63
      int jb = (q & 31) * 4;                // 0..124
      const float4 av = *reinterpret_cast<const float4*>(ab + (size_t)(i0 + k) * NJ + j0 + jb);
      // rotate (a0..a3) left by r via two conditional-swap stages (no dynamic idx)
      float a0 = av.x, a1 = av.y, a2 = av.z, a3 = av.w;
      bool s1 = (r & 1), s2 = (r & 2);
      float t0 = s1 ? a1 : a0, t1 = s1 ? a2 : a1, t2 = s1 ? a3 : a2, t3 = s1 ? a0 : a3;
      float u0 = s2 ? t2 : t0, u1 = s2 ? t3 : t1, u2 = s2 ? t0 : t2, u3 = s2 ? t1 : t3;
      // u_cc = a[(cc + r) & 3]
      int j0c = jb + ((0 + r) & 3);
      int j1c = jb + ((1 + r) & 3);
      int j2c = jb + ((2 + r) & 3);
      int j3c = jb + ((3 + r) & 3);
      bsum0 += u0; bsum1 += u1; bsum2 += u2; bsum3 += u3;
      Bs[j0c * 64 + (k ^ ((j0c & 7) << 3))] = f2bf(u0);
      Bs[j1c * 64 + (k ^ ((j1c & 7) << 3))] = f2bf(u1);
      Bs[j2c * 64 + (k ^ ((j2c & 7) << 3))] = f2bf(u2);
      Bs[j3c * 64 + (k ^ ((j3c & 7) << 3))] = f2bf(u3);
    }
    __syncthreads();

    // ---- MFMA over this K-chunk (2 k-steps of 32)
    #pragma unroll
    for (int ks = 0; ks < 2; ++ks) {
      const int k0 = ks * 32 + 8 * lk;
      bf16x8 af[8], bfr[2];
      #pragma unroll
      for (int m = 0; m < 8; ++m) {
        int row = wr * 128 + m * 16 + l15;
        af[m] = *reinterpret_cast<const bf16x8*>(&As[row * 64 + (k0 ^ ((row & 7) << 3))]);
      }
      #pragma unroll
      for (int n = 0; n < 2; ++n) {
        int row = wc * 32 + n * 16 + l15;
        bfr[n] = *reinterpret_cast<const bf16x8*>(&Bs[row * 64 + (k0 ^ ((row & 7) << 3))]);
      }
      #pragma unroll
      for (int m = 0; m < 8; ++m)
        #pragma unroll
        for (int n = 0; n < 2; ++n)
          C[m][n] = __builtin_amdgcn_mfma_f32_16x16x32_bf16(af[m], bfr[n], C[m][n], 0, 0, 0);
    }
    __syncthreads();
  }

  // ---- reduce per-thread column partials -> logS[j] (local j)
  {
    int jb = (lane & 31) * 4;
    int row = wid * 2 + (lane >> 5);        // 0..15, no same-addr collision
    colpart[row * JH + jb + ((0 + r) & 3)] = bsum0;
    colpart[row * JH + jb + ((1 + r) & 3)] = bsum1;
    colpart[row * JH + jb + ((2 + r) & 3)] = bsum2;
    colpart[row * JH + jb + ((3 + r) & 3)] = bsum3;
  }
  __syncthreads();
  if (tid < JH) {
    float s = 0.f;
    #pragma unroll
    for (int c = 0; c < 16; ++c) s += colpart[c * JH + tid];
    logS[tid] = __logf(s);
  }
  __syncthreads();

  // ---- epilogue: out[b][j0+j] = log(C) - logS[j]
  // C/D layout (16x16): col = lane&15, row = (lane>>4)*4 + reg
  #pragma unroll
  for (int m = 0; m < 8; ++m) {
    int b0 = wr * 128 + m * 16 + lk * 4;
    #pragma unroll
    for (int n = 0; n < 2; ++n) {
      int j = wc * 32 + n * 16 + l15;
      float ls = logS[j];
      #pragma unroll
      for (int rr = 0; rr < 4; ++rr) {
        ob[(size_t)(b0 + rr) * NJ + j0 + j] = __logf(C[m][n][rr]) - ls;
      }
    }
  }
}

extern "C" void kernel_launch(void* const* d_in, const int* in_sizes, int n_in,
                              void* d_out, int out_size, void* d_ws, size_t ws_size,
                              hipStream_t stream) {
  const float* x   = (const float*)d_in[0];
  const float* acc = (const float*)d_in[1];
  float* out = (float*)d_out;
  hipLaunchKernelGGL(densesum_kernel, dim3(NSC * NDC * 2), dim3(512), 0, stream, x, acc, out);
}